// Round 12
// baseline (26.923 us; speedup 1.0000x reference)
//
#include <hip/hip_runtime.h>
#include <stdint.h>

// ContrastLoss: B=2, M=2048, T=4096, K=16, DT=150
// Band bins of rfft(150) kept: k = 4..20 (17 bins). Mean-subtract & /dt cancel.
// Per-segment Goertzel -> normalized PSD -> closed-form loss from moments.
//
// k1 v4b: STREAM full rows (coalesced, 6.3 TB/s regime). 2 rows per
// 128-thread block; each wave stages its own 16 KB row via 16x
// global_load_lds16 (dst stride 256 floats = 1024 B per instr -- the
// round-11 bug was an i<<10 dst stride writing outside the tile).
// Goertzel core = r7's proven 4-lane-per-segment version.
// Block collapses its 2 rows -> ws planes of 2048 (147 KB).

#define T_LEN 4096
#define NROWS 4096      // B*M
#define DTLEN 150
#define NBIN 17
#define NBLK 2048       // 2 rows per block

typedef float v2f __attribute__((ext_vector_type(2)));

// c_k = 2*cos(2*pi*k/150), k = 4..21 (idx 17 is a dummy pad, never used)
__device__ __constant__ float C2TAB[18] = {
  1.9719921f, 1.9562952f, 1.9371663f, 1.9146390f, 1.8887527f, 1.8595530f,
  1.8270909f, 1.7914235f, 1.7526134f, 1.7107286f, 1.6658425f, 1.6180340f,
  1.5673869f, 1.5139901f, 1.4579372f, 1.3993267f, 1.3382612f, 1.2748480f
};

__device__ __forceinline__ void gload_lds16(const float* g, float* l) {
  __builtin_amdgcn_global_load_lds(
      (const __attribute__((address_space(1))) void*)g,
      (__attribute__((address_space(3))) void*)l,
      16, 0, 0);
}

// ---------------- Kernel 1: per-row PSD partials ----------------
// 2048 blocks x 128 threads (2 waves). Wave w owns row r = 2b+w.
// Within a wave: seg = lane>>2 (16 segs), g = lane&3 (bins 5/4/4/4).
__global__ __launch_bounds__(128) void psd_partials(const float* __restrict__ mo,
                                                    const int* __restrict__ offs,
                                                    float* __restrict__ ws) {
  __shared__ float tile[2 * T_LEN];   // 32768 B -> 4 blocks/CU
  __shared__ float sm[2][18];

  const int b = blockIdx.x;
  const int t = threadIdx.x;
  const int w = t >> 6;
  const int lane = t & 63;
  const int r = (b << 1) + w;

  const float* __restrict__ rowp = mo + ((size_t)r << 12);
  float* trow = &tile[w << 12];

  // stream the full 16 KB row, coalesced: 16 x (64 lanes x 16 B = 1024 B)
  // src advance: 256 floats/iter; dst advance: 256 floats/iter (matches HW
  // lane-linear fill of 64*16 B per instruction).
  #pragma unroll
  for (int i = 0; i < 16; ++i)
    gload_lds16(rowp + (i << 8) + (lane << 2), trow + (i << 8));
  __syncthreads();

  const int seg = lane >> 2;
  const int g = lane & 3;
  const int off = offs[(r << 4) + seg];
  // bin group: g0 -> tab 0..4 (5 bins), g1 -> 5..8, g2 -> 9..12, g3 -> 13..16
  const int boff = (g == 0) ? 0 : (1 + 4 * g);
  const v2f c01 = {C2TAB[boff], C2TAB[boff + 1]};
  const v2f c23 = {C2TAB[boff + 2], C2TAB[boff + 3]};
  const float c4 = C2TAB[boff + 4];

  v2f a01 = {0.f, 0.f}, a23 = {0.f, 0.f}, b01 = {0.f, 0.f}, b23 = {0.f, 0.f};
  float a4 = 0.f, b4 = 0.f;   // a = s1, b = s2

  const float* __restrict__ x = trow + off;   // off <= 3946, n <= 149 -> in row
  #pragma unroll 5
  for (int n = 0; n < DTLEN; n += 2) {
    const float x0 = x[n];
    const float x1 = x[n + 1];
    const v2f x0v = {x0, x0};
    const v2f x1v = {x1, x1};
    b01 = __builtin_elementwise_fma(c01, a01, x0v - b01);
    b23 = __builtin_elementwise_fma(c23, a23, x0v - b23);
    b4  = fmaf(c4, a4, x0 - b4);
    a01 = __builtin_elementwise_fma(c01, b01, x1v - a01);
    a23 = __builtin_elementwise_fma(c23, b23, x1v - a23);
    a4  = fmaf(c4, b4, x1 - a4);
  }

  // |X_k|^2 = s1^2 + s2^2 - c*s1*s2
  const v2f p01 = __builtin_elementwise_fma(a01, a01, b01 * b01) - c01 * (a01 * b01);
  const v2f p23 = __builtin_elementwise_fma(a23, a23, b23 * b23) - c23 * (a23 * b23);
  float p[5];
  p[0] = p01.x; p[1] = p01.y; p[2] = p23.x; p[3] = p23.y;
  p[4] = (g == 0) ? (fmaf(a4, a4, b4 * b4) - c4 * a4 * b4) : 0.0f;

  // per-seg band sum across this seg's 4 lanes
  float bs = p[0] + p[1] + p[2] + p[3] + p[4];
  bs += __shfl_xor(bs, 1, 64);
  bs += __shfl_xor(bs, 2, 64);
  const float inv = 1.0f / bs;
  #pragma unroll
  for (int j = 0; j < 5; ++j) p[j] *= inv;

  // row total sum of squares (all segs, all bins)
  float ssq = p[0]*p[0] + p[1]*p[1] + p[2]*p[2] + p[3]*p[3] + p[4]*p[4];
  #pragma unroll
  for (int m = 1; m <= 32; m <<= 1) ssq += __shfl_xor(ssq, m, 64);

  // column sums across segs (lanes with equal g, stride 4)
  #pragma unroll
  for (int m = 4; m <= 32; m <<= 1) {
    #pragma unroll
    for (int j = 0; j < 5; ++j) p[j] += __shfl_xor(p[j], m, 64);
  }

  // per-wave row results -> LDS, then collapse the block's 2 rows
  if (lane == 0) sm[w][0] = ssq;
  if (lane < 4) {
    const int nb = (lane == 0) ? 5 : 4;
    #pragma unroll
    for (int j = 0; j < 5; ++j)
      if (j < nb) sm[w][1 + boff + j] = p[j];
  }
  __syncthreads();

  // ws planes of 2048: ws[e*2048 + b], e=0 -> ssq, e=1..17 -> column sums
  if (t < 18) ws[(t << 11) + b] = sm[0][t] + sm[1][t];
}

// ------- Kernel 2: fused column reduction + closed-form scalar (1 block) -------
// 1024 threads = 16 waves. Pair p (0..35): e = p>>1, v = p&1, covers
// ws[e*2048 + v*1024 .. +1024). Wave w handles pairs {w, w+16, w+32}.
__global__ __launch_bounds__(1024) void reduce_final(const float* __restrict__ ws,
                                                     float* __restrict__ out) {
  __shared__ double fin[36];
  const int t = threadIdx.x;
  const int w = t >> 6, lane = t & 63;

  for (int p = w; p < 36; p += 16) {
    const float4* __restrict__ base =
        (const float4*)(ws + ((p >> 1) << 11) + ((p & 1) << 10));
    double a = 0.0;
    #pragma unroll
    for (int q = 0; q < 4; ++q) {
      float4 f = base[lane + (q << 6)];
      a += (double)f.x + (double)f.y + (double)f.z + (double)f.w;
    }
    #pragma unroll
    for (int m = 32; m >= 1; m >>= 1) a += __shfl_xor(a, m, 64);
    if (lane == 0) fin[p] = a;
  }
  __syncthreads();

  if (t == 0) {
    double sumA2 = fin[0], sumB2 = fin[1];
    double dAA = 0.0, dBB = 0.0, dAB = 0.0;
    #pragma unroll
    for (int f = 0; f < NBIN; ++f) {
      double ca = fin[2 * (1 + f)];
      double cb = fin[2 * (1 + f) + 1];
      dAA += ca * ca;
      dBB += cb * cb;
      dAB += ca * cb;
    }
    const double N = 32768.0;
    const double invFb  = 1.0 / 17.0;
    const double invNN1 = 1.0 / (32768.0 * 32767.0);
    const double invNN  = 1.0 / (32768.0 * 32768.0);
    double pAA = (2.0 * N * sumA2 - 2.0 * dAA) * invFb;
    double pBB = (2.0 * N * sumB2 - 2.0 * dBB) * invFb;
    double pAB = (N * sumA2 + N * sumB2 - 2.0 * dAB) * invFb;
    double selfa = pAA * invNN1;
    double selfb = pBB * invNN1;
    out[0] = (float)(0.5 * (selfa + selfb) + pAB * invNN);
  }
}

extern "C" void kernel_launch(void* const* d_in, const int* in_sizes, int n_in,
                              void* d_out, int out_size, void* d_ws, size_t ws_size,
                              hipStream_t stream) {
  const float* mo = (const float*)d_in[0];   // (2, 2048, 4096) f32
  const int* offs = (const int*)d_in[1];     // (2, 2048, 16) i32
  float* out = (float*)d_out;
  float* ws = (float*)d_ws;                  // 18*2048*4 = 147456 B used

  psd_partials<<<NBLK, 128, 0, stream>>>(mo, offs, ws);
  reduce_final<<<1, 1024, 0, stream>>>(ws, out);
}

// Round 13
// 20.943 us; speedup vs baseline: 1.2855x; 1.2855x over previous
//
#include <hip/hip_runtime.h>
#include <stdint.h>

// ContrastLoss: B=2, M=2048, T=4096, K=16, DT=150
// Band bins of rfft(150) kept: k = 4..20 (17 bins). Mean-subtract & /dt cancel.
// Per-segment Goertzel -> normalized PSD -> closed-form loss from moments.
//
// k1 v5: r7's proven per-wave scatter-gather (w16 global_load_lds, 12.7 us,
// the best measured memory regime) but 4 rows per 256-thread block; the 4
// rows' 18 partials are aggregated in-block (tile LDS reused after sync).
// ws shrinks 295 KB -> 74 KB (18 planes of 1024), cutting k2's read 4x.

#define T_LEN 4096
#define KSEG 16
#define NROWS 4096      // B*M
#define DTLEN 150
#define NBIN 17
#define SEG_STRIDE 156  // floats; 624 B = 39*16 -> every slot 16B-aligned

typedef float v2f __attribute__((ext_vector_type(2)));

// c_k = 2*cos(2*pi*k/150), k = 4..21 (idx 17 is a dummy pad, never used)
__device__ __constant__ float C2TAB[18] = {
  1.9719921f, 1.9562952f, 1.9371663f, 1.9146390f, 1.8887527f, 1.8595530f,
  1.8270909f, 1.7914235f, 1.7526134f, 1.7107286f, 1.6658425f, 1.6180340f,
  1.5673869f, 1.5139901f, 1.4579372f, 1.3993267f, 1.3382612f, 1.2748480f
};

__device__ __forceinline__ void gload_lds16(const float* g, float* l) {
  __builtin_amdgcn_global_load_lds(
      (const __attribute__((address_space(1))) void*)g,
      (__attribute__((address_space(3))) void*)l,
      16, 0, 0);
}

// ---------------- Kernel 1: per-row PSD partials, 4 rows/block ----------------
// 1024 blocks x 256 threads. Wave w owns row r = 4b+w (exactly r7's wave code).
// Within a wave: seg = lane>>2 (16 segs), g = lane&3 (bins 5/4/4/4).
__global__ __launch_bounds__(256) void psd_partials(const float* __restrict__ mo,
                                                    const int* __restrict__ offs,
                                                    float* __restrict__ ws) {
  __shared__ float tile[4 * KSEG * SEG_STRIDE];   // 39936 B -> 4 blocks/CU

  const int b = blockIdx.x;
  const int t = threadIdx.x;
  const int w = t >> 6;
  const int lane = t & 63;
  const int r = (b << 2) + w;

  const int seg = lane >> 2;
  const int g = lane & 3;
  const int off = offs[(r << 4) + seg];      // own seg's offset (4-lane broadcast)
  const float* __restrict__ rowp = mo + ((size_t)r << 12);
  float* twave = &tile[w * KSEG * SEG_STRIDE];

  // Stage 16 segments: one width-16 global_load_lds per segment.
  // Offset floored to 16B; phase (off&3) absorbed in the LDS read index.
  // Lanes 0..37 always needed; lane 38 only when phase==3 (off<=3946 keeps
  // all needed lanes inside the row).
  #pragma unroll
  for (int s = 0; s < KSEG; ++s) {
    const int off_s = __shfl(off, s << 2, 64);
    const int al = off_s & ~3;
    const int bound = 37 + ((off_s & 3) == 3);
    if (lane <= bound)
      gload_lds16(rowp + al + 4 * lane, &twave[s * SEG_STRIDE]);
  }
  __syncthreads();

  // bin group: g0 -> tab 0..4 (5 bins), g1 -> 5..8, g2 -> 9..12, g3 -> 13..16
  const int boff = (g == 0) ? 0 : (1 + 4 * g);
  const v2f c01 = {C2TAB[boff], C2TAB[boff + 1]};
  const v2f c23 = {C2TAB[boff + 2], C2TAB[boff + 3]};
  const float c4 = C2TAB[boff + 4];

  v2f a01 = {0.f, 0.f}, a23 = {0.f, 0.f}, b01 = {0.f, 0.f}, b23 = {0.f, 0.f};
  float a4 = 0.f, b4 = 0.f;   // a = s1, b = s2

  const float* __restrict__ x = &twave[seg * SEG_STRIDE + (off & 3)];
  #pragma unroll 5
  for (int n = 0; n < DTLEN; n += 2) {
    const float x0 = x[n];
    const float x1 = x[n + 1];
    const v2f x0v = {x0, x0};
    const v2f x1v = {x1, x1};
    b01 = __builtin_elementwise_fma(c01, a01, x0v - b01);
    b23 = __builtin_elementwise_fma(c23, a23, x0v - b23);
    b4  = fmaf(c4, a4, x0 - b4);
    a01 = __builtin_elementwise_fma(c01, b01, x1v - a01);
    a23 = __builtin_elementwise_fma(c23, b23, x1v - a23);
    a4  = fmaf(c4, b4, x1 - a4);
  }

  // |X_k|^2 = s1^2 + s2^2 - c*s1*s2
  const v2f p01 = __builtin_elementwise_fma(a01, a01, b01 * b01) - c01 * (a01 * b01);
  const v2f p23 = __builtin_elementwise_fma(a23, a23, b23 * b23) - c23 * (a23 * b23);
  float p[5];
  p[0] = p01.x; p[1] = p01.y; p[2] = p23.x; p[3] = p23.y;
  p[4] = (g == 0) ? (fmaf(a4, a4, b4 * b4) - c4 * a4 * b4) : 0.0f;

  // per-seg band sum across this seg's 4 lanes
  float bs = p[0] + p[1] + p[2] + p[3] + p[4];
  bs += __shfl_xor(bs, 1, 64);
  bs += __shfl_xor(bs, 2, 64);
  const float inv = 1.0f / bs;
  #pragma unroll
  for (int j = 0; j < 5; ++j) p[j] *= inv;

  // row total sum of squares (all segs, all bins)
  float ssq = p[0]*p[0] + p[1]*p[1] + p[2]*p[2] + p[3]*p[3] + p[4]*p[4];
  #pragma unroll
  for (int m = 1; m <= 32; m <<= 1) ssq += __shfl_xor(ssq, m, 64);

  // column sums across segs (lanes with equal g, stride 4)
  #pragma unroll
  for (int m = 4; m <= 32; m <<= 1) {
    #pragma unroll
    for (int j = 0; j < 5; ++j) p[j] += __shfl_xor(p[j], m, 64);
  }

  // ---- in-block aggregation of the 4 rows ----
  // All waves are done READING tile after this barrier; reuse tile[0..71]
  // as the 4x18 stash.
  __syncthreads();
  if (lane == 0) tile[w * 18] = ssq;
  if (lane < 4) {
    const int nb = (lane == 0) ? 5 : 4;
    #pragma unroll
    for (int j = 0; j < 5; ++j)
      if (j < nb) tile[w * 18 + 1 + boff + j] = p[j];
  }
  __syncthreads();

  // ws planes of 1024: ws[e*1024 + b], e=0 -> ssq, e=1..17 -> column sums
  if (t < 18)
    ws[(t << 10) + b] = tile[t] + tile[18 + t] + tile[36 + t] + tile[54 + t];
}

// ------- Kernel 2: fused column reduction + closed-form scalar (1 block) -------
// 1024 threads = 16 waves. Pair p (0..35): e = p>>1, v = p&1, covers
// ws[e*1024 + v*512 .. +512). Wave w handles pairs {w, w+16, w+32}.
__global__ __launch_bounds__(1024) void reduce_final(const float* __restrict__ ws,
                                                     float* __restrict__ out) {
  __shared__ double fin[36];
  const int t = threadIdx.x;
  const int w = t >> 6, lane = t & 63;

  for (int p = w; p < 36; p += 16) {
    const float4* __restrict__ base =
        (const float4*)(ws + ((p >> 1) << 10) + ((p & 1) << 9));
    float4 f0 = base[lane];        // 512 floats per pair = 128 float4
    float4 f1 = base[lane + 64];
    double a = (double)f0.x + (double)f0.y + (double)f0.z + (double)f0.w
             + (double)f1.x + (double)f1.y + (double)f1.z + (double)f1.w;
    #pragma unroll
    for (int m = 32; m >= 1; m >>= 1) a += __shfl_xor(a, m, 64);
    if (lane == 0) fin[p] = a;
  }
  __syncthreads();

  if (t == 0) {
    double sumA2 = fin[0], sumB2 = fin[1];
    double dAA = 0.0, dBB = 0.0, dAB = 0.0;
    #pragma unroll
    for (int f = 0; f < NBIN; ++f) {
      double ca = fin[2 * (1 + f)];
      double cb = fin[2 * (1 + f) + 1];
      dAA += ca * ca;
      dBB += cb * cb;
      dAB += ca * cb;
    }
    const double N = 32768.0;
    const double invFb  = 1.0 / 17.0;
    const double invNN1 = 1.0 / (32768.0 * 32767.0);
    const double invNN  = 1.0 / (32768.0 * 32768.0);
    double pAA = (2.0 * N * sumA2 - 2.0 * dAA) * invFb;
    double pBB = (2.0 * N * sumB2 - 2.0 * dBB) * invFb;
    double pAB = (N * sumA2 + N * sumB2 - 2.0 * dAB) * invFb;
    double selfa = pAA * invNN1;
    double selfb = pBB * invNN1;
    out[0] = (float)(0.5 * (selfa + selfb) + pAB * invNN);
  }
}

extern "C" void kernel_launch(void* const* d_in, const int* in_sizes, int n_in,
                              void* d_out, int out_size, void* d_ws, size_t ws_size,
                              hipStream_t stream) {
  const float* mo = (const float*)d_in[0];   // (2, 2048, 4096) f32
  const int* offs = (const int*)d_in[1];     // (2, 2048, 16) i32
  float* out = (float*)d_out;
  float* ws = (float*)d_ws;                  // 18*1024*4 = 73728 B used

  psd_partials<<<NROWS / 4, 256, 0, stream>>>(mo, offs, ws);
  reduce_final<<<1, 1024, 0, stream>>>(ws, out);
}